// Round 1
// baseline (44630.539 us; speedup 1.0000x reference)
//
#include <hip/hip_runtime.h>
#include <hip/hip_bf16.h>

#define T_ 512
#define B_ 128
#define D_ 256
#define H_ 256
#define EPS 1e-5f

typedef __attribute__((ext_vector_type(8))) short short8;
typedef __attribute__((ext_vector_type(4))) short short4v;
typedef __attribute__((ext_vector_type(4))) float f32x4;

// bf16 weight arena layout in d_ws (element offsets, bf16/short):
#define WT1A_OFF 0         // [768][512]  n: 0-255 Wr, 256-511 Wz, 512-767 Wl ; k: 0-255 x-part, 256-511 h-part
#define WT1B_OFF 393216    // [512][256]  n: 0-255 Cx, 256-511 Wlt            ; A = x
#define WT1C_OFF 524288    // [256][256]  Ch_w                                 ; A = h
#define WTT_OFF  589824    // [4][768][256] per layer: n 0-255 tWr, 256-511 tWz, 512-767 tWc
#define WTT_PER  196608
#define WT_TOTAL 1376256

__device__ __forceinline__ short f2bf(float f) {
  unsigned u = __builtin_bit_cast(unsigned, f);
  u = (u + 0x7FFFu + ((u >> 16) & 1u)) >> 16;   // RNE
  return (short)u;
}

__device__ __forceinline__ f32x4 zero4() { f32x4 z = {0.f, 0.f, 0.f, 0.f}; return z; }

__device__ __forceinline__ f32x4 mfma16(short8 a, short8 b, f32x4 c) {
  return __builtin_amdgcn_mfma_f32_16x16x32_bf16(a, b, c, 0, 0, 0);
}

__device__ __forceinline__ void red2(float& a, float& b) {
  #pragma unroll
  for (int off = 32; off; off >>= 1) {
    a += __shfl_xor(a, off);
    b += __shfl_xor(b, off);
  }
}

// LayerNorm over the 256 values held across the wave (4 per lane) -> sigmoid
__device__ __forceinline__ f32x4 ln_sig(f32x4 v, f32x4 g, f32x4 bb) {
  float s1 = v[0] + v[1] + v[2] + v[3];
  float s2 = v[0]*v[0] + v[1]*v[1] + v[2]*v[2] + v[3]*v[3];
  red2(s1, s2);
  float m = s1 * (1.f / 256.f);
  float var = s2 * (1.f / 256.f) - m * m;
  float rs = rsqrtf((var > 0.f ? var : 0.f) + EPS);
  f32x4 o;
  #pragma unroll
  for (int i = 0; i < 4; ++i) {
    float t = (v[i] - m) * rs * g[i] + bb[i];
    o[i] = 1.f / (1.f + __expf(-t));
  }
  return o;
}

// ---------------- weight prep: f32 -> bf16, transposed to [n][k] ----------------
__global__ void prep_weights(const float* __restrict__ Wr, const float* __restrict__ Wz,
                             const float* __restrict__ Wl, const float* __restrict__ Wlt,
                             const float* __restrict__ Cx, const float* __restrict__ Chw,
                             const float* __restrict__ tWr, const float* __restrict__ tWz,
                             const float* __restrict__ tWc, short* __restrict__ wt) {
  int idx = blockIdx.x * 256 + threadIdx.x;
  if (idx >= WT_TOTAL) return;
  float v;
  if (idx < WT1B_OFF) {                       // WT1a [768][512]
    int n = idx >> 9, k = idx & 511;
    const float* W = (n < 256) ? Wr : (n < 512 ? Wz : Wl);
    v = W[k * 256 + (n & 255)];
  } else if (idx < WT1C_OFF) {                // WT1b [512][256]
    int r = idx - WT1B_OFF;
    int n = r >> 8, k = r & 255;
    v = (n < 256) ? Cx[k * 256 + n] : Wlt[k * 256 + (n - 256)];
  } else if (idx < WTT_OFF) {                 // WT1c [256][256]
    int r = idx - WT1C_OFF;
    int n = r >> 8, k = r & 255;
    v = Chw[k * 256 + n];
  } else {                                    // WTt [4][768][256]
    int r = idx - WTT_OFF;
    int i = r / WTT_PER;
    int rr = r - i * WTT_PER;
    int n = rr >> 8, k = rr & 255;
    const float* W = (n < 256) ? tWr : (n < 512 ? tWz : tWc);
    v = W[(i * 256 + k) * 256 + (n & 255)];
  }
  wt[idx] = f2bf(v);
}

// ---------------- persistent recurrent kernel: 8 WGs x 16 batch rows ----------------
__global__ __launch_bounds__(512, 2)
void rnn_persistent(const float* __restrict__ x, const int* __restrict__ lengths,
                    const float* __restrict__ gr, const float* __restrict__ br,
                    const float* __restrict__ gz, const float* __restrict__ bz,
                    const float* __restrict__ gl, const float* __restrict__ bl,
                    const float* __restrict__ Chb,
                    const float* __restrict__ tgr, const float* __restrict__ tbr,
                    const float* __restrict__ tgz, const float* __restrict__ tbz,
                    const float* __restrict__ tbc,
                    const short* __restrict__ W, float* __restrict__ out) {

  __shared__ __align__(16) char smem[115712];
  char*  HBF = smem;                       // [16][256] bf16, XOR-swizzled   (8 KB)
  char*  XBF = smem + 8192;                // [16][256] bf16, XOR-swizzled   (8 KB)
  float* G   = (float*)(smem + 16384);     // [16][776] f32 gate buffer      (48.5 KB)
  float* G2  = (float*)(smem + 66048);     // [16][776] f32 (xCx|xWlt|hCh)   (48.5 KB)

  const int tid = threadIdx.x;
  const int w   = tid >> 6, l = tid & 63;
  const int la  = l & 15, lh = l >> 4;     // MFMA lane coords
  const int rb0 = blockIdx.x * 16;
  const int c0  = 4 * l;                   // elementwise columns 4l..4l+3
  const int amask = (la & 7) << 4;         // LDS swizzle mask for A-frag reads

  // zero h in LDS (bf16 view)
  for (int i = tid; i < 16 * 256 / 4; i += 512) ((short4v*)HBF)[i] = (short4v){0, 0, 0, 0};

  const int lenA = lengths[rb0 + 2 * w];
  const int lenB = lengths[rb0 + 2 * w + 1];
  int maxlen = 0;
  for (int i = 0; i < 16; ++i) {
    int v = lengths[rb0 + i];
    maxlen = maxlen > v ? maxlen : v;
  }

  f32x4 hA = zero4(), hB = zero4();        // f32 h state: wave w owns rows 2w, 2w+1

  __syncthreads();

  for (int t = 0; t < maxlen; ++t) {
    // ---- phase A: stage x_t -> XBF (bf16, swizzled) ----
    {
      const float* xt = x + ((size_t)t * B_ + rb0) * D_;
      for (int c = tid; c < 1024; c += 512) {
        int row = c >> 6, j = c & 63;
        f32x4 v = *(const f32x4*)(xt + row * D_ + 4 * j);
        short4v s = { f2bf(v[0]), f2bf(v[1]), f2bf(v[2]), f2bf(v[3]) };
        *(short4v*)(XBF + row * 512 + ((8 * j) ^ ((row & 7) << 4))) = s;
      }
    }
    __syncthreads();

    // ---- phase B1: x@[Cx|Wlt] and h@Ch_w -> G2 ----
    {
      f32x4 acc2[4], acc3[2];
      #pragma unroll
      for (int s = 0; s < 4; ++s) acc2[s] = zero4();
      #pragma unroll
      for (int s = 0; s < 2; ++s) acc3[s] = zero4();
      const short* b2 = W + WT1B_OFF + ((w * 4) * 16 + la) * 256 + lh * 8;
      const short* b3 = W + WT1C_OFF + ((w * 2) * 16 + la) * 256 + lh * 8;
      #pragma unroll 2
      for (int kf = 0; kf < 8; ++kf) {
        int aoff = la * 512 + (((kf * 64) + lh * 16) ^ amask);
        short8 ax = *(const short8*)(XBF + aoff);
        short8 ah = *(const short8*)(HBF + aoff);
        #pragma unroll
        for (int s = 0; s < 4; ++s)
          acc2[s] = mfma16(ax, *(const short8*)(b2 + s * 16 * 256 + kf * 32), acc2[s]);
        #pragma unroll
        for (int s = 0; s < 2; ++s)
          acc3[s] = mfma16(ah, *(const short8*)(b3 + s * 16 * 256 + kf * 32), acc3[s]);
      }
      #pragma unroll
      for (int s = 0; s < 4; ++s)
        #pragma unroll
        for (int i = 0; i < 4; ++i)
          G2[(lh * 4 + i) * 776 + (w * 4 + s) * 16 + la] = acc2[s][i];
      #pragma unroll
      for (int s = 0; s < 2; ++s)
        #pragma unroll
        for (int i = 0; i < 4; ++i)
          G2[(lh * 4 + i) * 776 + 512 + (w * 2 + s) * 16 + la] = acc3[s][i];
    }
    // ---- phase B2: [x|h] @ [Wr|Wz|Wl] (K=512) -> G ----
    {
      f32x4 acc[6];
      #pragma unroll
      for (int s = 0; s < 6; ++s) acc[s] = zero4();
      const short* bg = W + WT1A_OFF + ((w * 6) * 16 + la) * 512 + lh * 8;
      #pragma unroll 4
      for (int kf = 0; kf < 16; ++kf) {
        int kl = kf & 7;
        int aoff = la * 512 + (((kl * 64) + lh * 16) ^ amask);
        short8 a = (kf < 8) ? *(const short8*)(XBF + aoff) : *(const short8*)(HBF + aoff);
        #pragma unroll
        for (int s = 0; s < 6; ++s)
          acc[s] = mfma16(a, *(const short8*)(bg + s * 16 * 512 + kf * 32), acc[s]);
      }
      #pragma unroll
      for (int s = 0; s < 6; ++s)
        #pragma unroll
        for (int i = 0; i < 4; ++i)
          G[(lh * 4 + i) * 776 + (w * 6 + s) * 16 + la] = acc[s][i];
    }
    __syncthreads();

    // ---- phase C: GRU cell elementwise (wave w -> rows 2w, 2w+1) ----
    {
      f32x4 g4r = *(const f32x4*)(gr + c0), b4r = *(const f32x4*)(br + c0);
      f32x4 g4z = *(const f32x4*)(gz + c0), b4z = *(const f32x4*)(bz + c0);
      f32x4 g4l = *(const f32x4*)(gl + c0), b4l = *(const f32x4*)(bl + c0);
      f32x4 cb4 = *(const f32x4*)(Chb + c0);
      #pragma unroll
      for (int rr = 0; rr < 2; ++rr) {
        int row = 2 * w + rr;
        f32x4 pr  = *(const f32x4*)&G[row * 776 + c0];
        f32x4 pz  = *(const f32x4*)&G[row * 776 + 256 + c0];
        f32x4 pl  = *(const f32x4*)&G[row * 776 + 512 + c0];
        f32x4 xcx = *(const f32x4*)&G2[row * 776 + c0];
        f32x4 xwl = *(const f32x4*)&G2[row * 776 + 256 + c0];
        f32x4 hch = *(const f32x4*)&G2[row * 776 + 512 + c0];
        f32x4 r4 = ln_sig(pr, g4r, b4r);
        f32x4 z4 = ln_sig(pz, g4z, b4z);
        f32x4 l4 = ln_sig(pl, g4l, b4l);
        f32x4 h = rr ? hB : hA;
        f32x4 hn;
        #pragma unroll
        for (int i = 0; i < 4; ++i) {
          float n = tanhf(xcx[i] + r4[i] * (hch[i] + cb4[i])) + l4[i] * xwl[i];
          hn[i] = (1.f - z4[i]) * h[i] + z4[i] * n;
        }
        bool act = t < (rr ? lenB : lenA);
        if (act) {
          if (rr) hB = hn; else hA = hn;
          short4v sv = { f2bf(hn[0]), f2bf(hn[1]), f2bf(hn[2]), f2bf(hn[3]) };
          *(short4v*)(HBF + row * 512 + ((8 * l) ^ ((row & 7) << 4))) = sv;
        }
      }
    }
    __syncthreads();

    // ---- phases D/E: 4 transition layers ----
    #pragma unroll 1
    for (int li = 0; li < 4; ++li) {
      f32x4 acc[6];
      #pragma unroll
      for (int s = 0; s < 6; ++s) acc[s] = zero4();
      const short* bt = W + WTT_OFF + li * WTT_PER + ((w * 6) * 16 + la) * 256 + lh * 8;
      #pragma unroll 4
      for (int kf = 0; kf < 8; ++kf) {
        int aoff = la * 512 + (((kf * 64) + lh * 16) ^ amask);
        short8 a = *(const short8*)(HBF + aoff);
        #pragma unroll
        for (int s = 0; s < 6; ++s)
          acc[s] = mfma16(a, *(const short8*)(bt + s * 16 * 256 + kf * 32), acc[s]);
      }
      #pragma unroll
      for (int s = 0; s < 6; ++s)
        #pragma unroll
        for (int i = 0; i < 4; ++i)
          G[(lh * 4 + i) * 776 + (w * 6 + s) * 16 + la] = acc[s][i];
      __syncthreads();
      {
        f32x4 g4r = *(const f32x4*)(tgr + li * 256 + c0), b4r = *(const f32x4*)(tbr + li * 256 + c0);
        f32x4 g4z = *(const f32x4*)(tgz + li * 256 + c0), b4z = *(const f32x4*)(tbz + li * 256 + c0);
        f32x4 cb4 = *(const f32x4*)(tbc + li * 256 + c0);
        #pragma unroll
        for (int rr = 0; rr < 2; ++rr) {
          int row = 2 * w + rr;
          f32x4 pr = *(const f32x4*)&G[row * 776 + c0];
          f32x4 pz = *(const f32x4*)&G[row * 776 + 256 + c0];
          f32x4 pc = *(const f32x4*)&G[row * 776 + 512 + c0];
          f32x4 ri = ln_sig(pr, g4r, b4r);
          f32x4 zi = ln_sig(pz, g4z, b4z);
          f32x4 h = rr ? hB : hA;
          f32x4 hn;
          #pragma unroll
          for (int i = 0; i < 4; ++i) {
            float n = tanhf(ri[i] * (pc[i] + cb4[i]));
            hn[i] = (1.f - zi[i]) * n + zi[i] * h[i];
          }
          bool act = t < (rr ? lenB : lenA);
          if (act) {
            if (rr) hB = hn; else hA = hn;
            short4v sv = { f2bf(hn[0]), f2bf(hn[1]), f2bf(hn[2]), f2bf(hn[3]) };
            *(short4v*)(HBF + row * 512 + ((8 * l) ^ ((row & 7) << 4))) = sv;
          }
          if (li == 3) {
            f32x4 o = act ? hn : zero4();
            *(f32x4*)(out + ((size_t)t * B_ + rb0 + row) * H_ + c0) = o;
          }
        }
      }
      if (li < 3) __syncthreads();
    }
  }

  // tail: zero outputs past this WG's longest sequence
  for (int t = maxlen; t < T_; ++t) {
    float* o = out + ((size_t)t * B_ + rb0) * H_;
    for (int i = tid; i < 16 * H_ / 4; i += 512)
      ((f32x4*)o)[i] = zero4();
  }
}

extern "C" void kernel_launch(void* const* d_in, const int* in_sizes, int n_in,
                              void* d_out, int out_size, void* d_ws, size_t ws_size,
                              hipStream_t stream) {
  const float* x    = (const float*)d_in[0];
  const int* lengths = (const int*)d_in[1];
  const float* Wr   = (const float*)d_in[2];
  const float* gr   = (const float*)d_in[3];
  const float* br   = (const float*)d_in[4];
  const float* Wz   = (const float*)d_in[5];
  const float* gz   = (const float*)d_in[6];
  const float* bz   = (const float*)d_in[7];
  const float* Wl   = (const float*)d_in[8];
  const float* gl   = (const float*)d_in[9];
  const float* bl   = (const float*)d_in[10];
  const float* Wlt  = (const float*)d_in[11];
  const float* Cx   = (const float*)d_in[12];
  const float* Chw  = (const float*)d_in[13];
  const float* Chb  = (const float*)d_in[14];
  const float* tWr  = (const float*)d_in[15];
  const float* tgr  = (const float*)d_in[16];
  const float* tbr  = (const float*)d_in[17];
  const float* tWz  = (const float*)d_in[18];
  const float* tgz  = (const float*)d_in[19];
  const float* tbz  = (const float*)d_in[20];
  const float* tWc  = (const float*)d_in[21];
  const float* tbc  = (const float*)d_in[22];

  short* wt = (short*)d_ws;

  hipLaunchKernelGGL(prep_weights, dim3((WT_TOTAL + 255) / 256), dim3(256), 0, stream,
                     Wr, Wz, Wl, Wlt, Cx, Chw, tWr, tWz, tWc, wt);
  hipLaunchKernelGGL(rnn_persistent, dim3(8), dim3(512), 0, stream,
                     x, lengths, gr, br, gz, bz, gl, bl, Chb,
                     tgr, tbr, tgz, tbz, tbc, wt, (float*)d_out);
}

// Round 2
// 38471.649 us; speedup vs baseline: 1.1601x; 1.1601x over previous
//
#include <hip/hip_runtime.h>
#include <hip/hip_bf16.h>

#define T_ 512
#define B_ 128
#define D_ 256
#define H_ 256
#define EPS 1e-5f

typedef __attribute__((ext_vector_type(8))) short short8;
typedef __attribute__((ext_vector_type(4))) short short4v;
typedef __attribute__((ext_vector_type(4))) float f32x4;

// bf16 weight arena layout in d_ws (element offsets, bf16/short):
#define WT1A_OFF 0         // [768][512]  n: 0-255 Wr, 256-511 Wz, 512-767 Wl ; k: 0-255 x, 256-511 h
#define WT1B_OFF 393216    // [512][256]  n: 0-255 Cx, 256-511 Wlt            ; A = x
#define WT1C_OFF 524288    // [256][256]  Ch_w                                 ; A = h
#define WTT_OFF  589824    // [4][768][256] per layer: n 0-255 tWr, 256-511 tWz, 512-767 tWc
#define WTT_PER  196608
#define WT_TOTAL 1376256

// ws byte offsets past the weight arena
#define PRE_OFFB  2752512UL   // f32 [2 parity][8 cl][6 arr][16][256]  (1.57 MB)
#define FLAG_OFFB 4325376UL   // u32 [8 cl][2560 events]               (80 KB)
#define NFLAGS    20480

__device__ __forceinline__ short f2bf(float f) {
  unsigned u = __builtin_bit_cast(unsigned, f);
  u = (u + 0x7FFFu + ((u >> 16) & 1u)) >> 16;   // RNE
  return (short)u;
}

__device__ __forceinline__ f32x4 zero4() { f32x4 z = {0.f, 0.f, 0.f, 0.f}; return z; }

__device__ __forceinline__ f32x4 mfma16(short8 a, short8 b, f32x4 c) {
  return __builtin_amdgcn_mfma_f32_16x16x32_bf16(a, b, c, 0, 0, 0);
}

__device__ __forceinline__ void red2(float& a, float& b) {
  #pragma unroll
  for (int off = 32; off; off >>= 1) {
    a += __shfl_xor(a, off);
    b += __shfl_xor(b, off);
  }
}

// LayerNorm over 256 values spread across the wave (4/lane) -> sigmoid
__device__ __forceinline__ f32x4 ln_sig(f32x4 v, f32x4 g, f32x4 bb) {
  float s1 = v[0] + v[1] + v[2] + v[3];
  float s2 = v[0]*v[0] + v[1]*v[1] + v[2]*v[2] + v[3]*v[3];
  red2(s1, s2);
  float m = s1 * (1.f / 256.f);
  float var = s2 * (1.f / 256.f) - m * m;
  float rs = rsqrtf((var > 0.f ? var : 0.f) + EPS);
  f32x4 o;
  #pragma unroll
  for (int i = 0; i < 4; ++i) {
    float t = (v[i] - m) * rs * g[i] + bb[i];
    o[i] = 1.f / (1.f + __expf(-t));
  }
  return o;
}

// device-coherent (AGENT scope) 16B load / 4B store into the shared preact buffer
__device__ __forceinline__ f32x4 ald4(float* p) {
  unsigned long long* q = (unsigned long long*)p;
  unsigned long long a = __hip_atomic_load(q,     __ATOMIC_RELAXED, __HIP_MEMORY_SCOPE_AGENT);
  unsigned long long b = __hip_atomic_load(q + 1, __ATOMIC_RELAXED, __HIP_MEMORY_SCOPE_AGENT);
  f32x4 v;
  v[0] = __builtin_bit_cast(float, (unsigned)(a & 0xffffffffu));
  v[1] = __builtin_bit_cast(float, (unsigned)(a >> 32));
  v[2] = __builtin_bit_cast(float, (unsigned)(b & 0xffffffffu));
  v[3] = __builtin_bit_cast(float, (unsigned)(b >> 32));
  return v;
}
__device__ __forceinline__ void ast1(float* p, float v) {
  __hip_atomic_store((unsigned*)p, __builtin_bit_cast(unsigned, v),
                     __ATOMIC_RELAXED, __HIP_MEMORY_SCOPE_AGENT);
}

// ---------------- weight prep: f32 -> bf16, transposed to [n][k] ----------------
__global__ void prep_weights(const float* __restrict__ Wr, const float* __restrict__ Wz,
                             const float* __restrict__ Wl, const float* __restrict__ Wlt,
                             const float* __restrict__ Cx, const float* __restrict__ Chw,
                             const float* __restrict__ tWr, const float* __restrict__ tWz,
                             const float* __restrict__ tWc, short* __restrict__ wt) {
  int idx = blockIdx.x * 256 + threadIdx.x;
  if (idx >= WT_TOTAL) return;
  float v;
  if (idx < WT1B_OFF) {                       // WT1a [768][512]
    int n = idx >> 9, k = idx & 511;
    const float* W = (n < 256) ? Wr : (n < 512 ? Wz : Wl);
    v = W[k * 256 + (n & 255)];
  } else if (idx < WT1C_OFF) {                // WT1b [512][256]
    int r = idx - WT1B_OFF;
    int n = r >> 8, k = r & 255;
    v = (n < 256) ? Cx[k * 256 + n] : Wlt[k * 256 + (n - 256)];
  } else if (idx < WTT_OFF) {                 // WT1c [256][256]
    int r = idx - WT1C_OFF;
    int n = r >> 8, k = r & 255;
    v = Chw[k * 256 + n];
  } else {                                    // WTt [4][768][256]
    int r = idx - WTT_OFF;
    int i = r / WTT_PER;
    int rr = r - i * WTT_PER;
    int n = rr >> 8, k = rr & 255;
    const float* W = (n < 256) ? tWr : (n < 512 ? tWz : tWc);
    v = W[(i * 256 + k) * 256 + (n & 255)];
  }
  wt[idx] = f2bf(v);
}

// ------- cluster kernel: 8 clusters (16 rows) x 16 col-slice WGs, 256 thr -------
__global__ __launch_bounds__(256)
void rnn_cluster(const float* __restrict__ x, const int* __restrict__ lengths,
                 const float* __restrict__ gr, const float* __restrict__ br,
                 const float* __restrict__ gz, const float* __restrict__ bz,
                 const float* __restrict__ gl, const float* __restrict__ bl,
                 const float* __restrict__ Chb,
                 const float* __restrict__ tgr, const float* __restrict__ tbr,
                 const float* __restrict__ tgz, const float* __restrict__ tbz,
                 const float* __restrict__ tbc,
                 const short* __restrict__ W, float* __restrict__ pre,
                 unsigned* __restrict__ flags, float* __restrict__ out) {

  __shared__ __align__(16) char smem[32768];
  char*  HBF = smem;                       // [16][256] bf16, XOR-swizzled (8 KB)
  char*  XBF = smem + 8192;                // [16][256] bf16, XOR-swizzled (8 KB)
  float* HF  = (float*)(smem + 16384);     // [16][256] f32 h master       (16 KB)

  const int tid = threadIdx.x;
  const int w   = tid >> 6, l = tid & 63;
  const int la  = l & 15, lh = l >> 4;
  const int amask = (la & 7) << 4;
  const int bid = blockIdx.x;
  const int cl  = bid & 7;                 // cluster (likely one XCD: round-robin dispatch)
  const int sl  = bid >> 3;                // column slice 0..15
  const int rb0 = cl * 16;                 // batch rows
  const int c0  = sl * 16;                 // output columns [c0, c0+16)
  const int c0e = 4 * l;                   // elementwise columns 4l..4l+3

  for (int i = tid; i < 1024; i += 256) ((short4v*)HBF)[i] = (short4v){0, 0, 0, 0};
  for (int i = tid; i < 1024; i += 256) ((f32x4*)HF)[i] = zero4();

  int maxlen = 0;
  for (int i = 0; i < 16; ++i) {
    int v = lengths[rb0 + i];
    maxlen = maxlen > v ? maxlen : v;
  }
  int lenr[4];
  #pragma unroll
  for (int i = 0; i < 4; ++i) lenr[i] = lengths[rb0 + 4 * w + i];

  unsigned* fbase = flags + cl * 2560;
  int dead = 0;                            // latched sync-timeout (tid 0 only)

  __syncthreads();

  for (int t = 0; t < maxlen; ++t) {
    // ---- stage x_t -> XBF (bf16, swizzled) ----
    {
      const float* xt = x + ((size_t)t * B_ + rb0) * D_;
      for (int c = tid; c < 1024; c += 256) {
        int row = c >> 6, j = c & 63;
        f32x4 v = *(const f32x4*)(xt + row * D_ + 4 * j);
        short4v s = { f2bf(v[0]), f2bf(v[1]), f2bf(v[2]), f2bf(v[3]) };
        *(short4v*)(XBF + row * 512 + ((8 * j) ^ ((row & 7) << 4))) = s;
      }
    }
    __syncthreads();

    // ================= round G =================
    int R = t * 5;
    {
      float* P = pre + (size_t)(((R & 1) * 8 + cl) * 6) * 4096;
      if (w < 3) {                         // waves 0..2: gate w slice, K=512
        f32x4 acc = zero4();
        const short* bp = W + WT1A_OFF + (size_t)(w * 256 + c0 + la) * 512 + lh * 8;
        #pragma unroll
        for (int kf = 0; kf < 16; ++kf) {
          int aoff = la * 512 + ((((kf & 7) * 64) + lh * 16) ^ amask);
          short8 a = (kf < 8) ? *(const short8*)(XBF + aoff) : *(const short8*)(HBF + aoff);
          acc = mfma16(a, *(const short8*)(bp + kf * 32), acc);
        }
        #pragma unroll
        for (int i = 0; i < 4; ++i) ast1(P + w * 4096 + (lh * 4 + i) * 256 + c0 + la, acc[i]);
      } else {                             // wave 3: xcx, xwl, hch (K=256)
        f32x4 a0 = zero4(), a1 = zero4(), a2 = zero4();
        const short* b0 = W + WT1B_OFF + (size_t)(c0 + la) * 256 + lh * 8;
        const short* b1 = W + WT1B_OFF + (size_t)(256 + c0 + la) * 256 + lh * 8;
        const short* b2 = W + WT1C_OFF + (size_t)(c0 + la) * 256 + lh * 8;
        #pragma unroll
        for (int kf = 0; kf < 8; ++kf) {
          int aoff = la * 512 + (((kf * 64) + lh * 16) ^ amask);
          short8 ax = *(const short8*)(XBF + aoff);
          short8 ah = *(const short8*)(HBF + aoff);
          a0 = mfma16(ax, *(const short8*)(b0 + kf * 32), a0);
          a1 = mfma16(ax, *(const short8*)(b1 + kf * 32), a1);
          a2 = mfma16(ah, *(const short8*)(b2 + kf * 32), a2);
        }
        #pragma unroll
        for (int i = 0; i < 4; ++i) {
          ast1(P + 3 * 4096 + (lh * 4 + i) * 256 + c0 + la, a0[i]);
          ast1(P + 4 * 4096 + (lh * 4 + i) * 256 + c0 + la, a1[i]);
          ast1(P + 5 * 4096 + (lh * 4 + i) * 256 + c0 + la, a2[i]);
        }
      }
      // ---- cluster sync R ----
      __threadfence();
      __syncthreads();
      if (tid == 0) {
        unsigned* f = fbase + R;
        __hip_atomic_fetch_add(f, 1u, __ATOMIC_RELEASE, __HIP_MEMORY_SCOPE_AGENT);
        if (!dead) {
          int it = 0;
          while (__hip_atomic_load(f, __ATOMIC_RELAXED, __HIP_MEMORY_SCOPE_AGENT) < 16u) {
            if (++it > 1000000) { dead = 1; break; }
            __builtin_amdgcn_s_sleep(4);
          }
        }
      }
      __syncthreads();

      // ---- redundant GRU-cell elementwise: wave w -> rows 4w..4w+3 ----
      f32x4 g4r = *(const f32x4*)(gr + c0e), b4r = *(const f32x4*)(br + c0e);
      f32x4 g4z = *(const f32x4*)(gz + c0e), b4z = *(const f32x4*)(bz + c0e);
      f32x4 g4l = *(const f32x4*)(gl + c0e), b4l = *(const f32x4*)(bl + c0e);
      f32x4 cb4 = *(const f32x4*)(Chb + c0e);
      #pragma unroll
      for (int i = 0; i < 4; ++i) {
        int row = 4 * w + i;
        float* Pr = P + row * 256 + c0e;
        f32x4 pr  = ald4(Pr);
        f32x4 pz  = ald4(Pr + 4096);
        f32x4 pl  = ald4(Pr + 2 * 4096);
        f32x4 xcx = ald4(Pr + 3 * 4096);
        f32x4 xwl = ald4(Pr + 4 * 4096);
        f32x4 hch = ald4(Pr + 5 * 4096);
        f32x4 r4 = ln_sig(pr, g4r, b4r);
        f32x4 z4 = ln_sig(pz, g4z, b4z);
        f32x4 l4 = ln_sig(pl, g4l, b4l);
        f32x4 h = *(const f32x4*)&HF[row * 256 + c0e];
        f32x4 hn;
        #pragma unroll
        for (int q = 0; q < 4; ++q) {
          float n = tanhf(xcx[q] + r4[q] * (hch[q] + cb4[q])) + l4[q] * xwl[q];
          hn[q] = (1.f - z4[q]) * h[q] + z4[q] * n;
        }
        if (t < lenr[i]) {
          *(f32x4*)&HF[row * 256 + c0e] = hn;
          short4v sv = { f2bf(hn[0]), f2bf(hn[1]), f2bf(hn[2]), f2bf(hn[3]) };
          *(short4v*)(HBF + row * 512 + ((8 * l) ^ ((row & 7) << 4))) = sv;
        }
      }
    }
    __syncthreads();

    // ================= transition layers =================
    #pragma unroll 1
    for (int li = 0; li < 4; ++li) {
      R = t * 5 + 1 + li;
      float* P = pre + (size_t)(((R & 1) * 8 + cl) * 6) * 4096;
      if (w < 3) {                         // waves 0..2: tr/tz/tc slice, K=256
        f32x4 acc = zero4();
        const short* bp = W + WTT_OFF + li * WTT_PER + (size_t)(w * 256 + c0 + la) * 256 + lh * 8;
        #pragma unroll
        for (int kf = 0; kf < 8; ++kf) {
          int aoff = la * 512 + (((kf * 64) + lh * 16) ^ amask);
          short8 a = *(const short8*)(HBF + aoff);
          acc = mfma16(a, *(const short8*)(bp + kf * 32), acc);
        }
        #pragma unroll
        for (int i = 0; i < 4; ++i) ast1(P + w * 4096 + (lh * 4 + i) * 256 + c0 + la, acc[i]);
      }
      // ---- cluster sync R ----
      __threadfence();
      __syncthreads();
      if (tid == 0) {
        unsigned* f = fbase + R;
        __hip_atomic_fetch_add(f, 1u, __ATOMIC_RELEASE, __HIP_MEMORY_SCOPE_AGENT);
        if (!dead) {
          int it = 0;
          while (__hip_atomic_load(f, __ATOMIC_RELAXED, __HIP_MEMORY_SCOPE_AGENT) < 16u) {
            if (++it > 1000000) { dead = 1; break; }
            __builtin_amdgcn_s_sleep(4);
          }
        }
      }
      __syncthreads();

      // ---- redundant transition elementwise ----
      f32x4 g4r = *(const f32x4*)(tgr + li * 256 + c0e), b4r = *(const f32x4*)(tbr + li * 256 + c0e);
      f32x4 g4z = *(const f32x4*)(tgz + li * 256 + c0e), b4z = *(const f32x4*)(tbz + li * 256 + c0e);
      f32x4 cb4 = *(const f32x4*)(tbc + li * 256 + c0e);
      #pragma unroll
      for (int i = 0; i < 4; ++i) {
        int row = 4 * w + i;
        float* Pr = P + row * 256 + c0e;
        f32x4 pr = ald4(Pr);
        f32x4 pz = ald4(Pr + 4096);
        f32x4 pc = ald4(Pr + 2 * 4096);
        f32x4 ri = ln_sig(pr, g4r, b4r);
        f32x4 zi = ln_sig(pz, g4z, b4z);
        f32x4 h = *(const f32x4*)&HF[row * 256 + c0e];
        f32x4 hn;
        #pragma unroll
        for (int q = 0; q < 4; ++q) {
          float n = tanhf(ri[q] * (pc[q] + cb4[q]));
          hn[q] = (1.f - zi[q]) * n + zi[q] * h[q];
        }
        bool act = t < lenr[i];
        if (act) {
          *(f32x4*)&HF[row * 256 + c0e] = hn;
          short4v sv = { f2bf(hn[0]), f2bf(hn[1]), f2bf(hn[2]), f2bf(hn[3]) };
          *(short4v*)(HBF + row * 512 + ((8 * l) ^ ((row & 7) << 4))) = sv;
        }
        if (li == 3 && (l >> 2) == sl) {   // this WG owns cols [c0,c0+16)
          f32x4 o = act ? hn : zero4();
          *(f32x4*)(out + ((size_t)t * B_ + rb0 + row) * H_ + c0e) = o;
        }
      }
      __syncthreads();
    }
  }

  // tail: zero this WG's column slice past the cluster's longest sequence
  for (int t = maxlen; t < T_; ++t) {
    if (tid < 64) {
      int row = tid >> 2, cc = (tid & 3) * 4;
      *(f32x4*)(out + ((size_t)t * B_ + rb0 + row) * H_ + c0 + cc) = zero4();
    }
  }
}

extern "C" void kernel_launch(void* const* d_in, const int* in_sizes, int n_in,
                              void* d_out, int out_size, void* d_ws, size_t ws_size,
                              hipStream_t stream) {
  const float* x    = (const float*)d_in[0];
  const int* lengths = (const int*)d_in[1];
  const float* Wr   = (const float*)d_in[2];
  const float* gr   = (const float*)d_in[3];
  const float* br   = (const float*)d_in[4];
  const float* Wz   = (const float*)d_in[5];
  const float* gz   = (const float*)d_in[6];
  const float* bz   = (const float*)d_in[7];
  const float* Wl   = (const float*)d_in[8];
  const float* gl   = (const float*)d_in[9];
  const float* bl   = (const float*)d_in[10];
  const float* Wlt  = (const float*)d_in[11];
  const float* Cx   = (const float*)d_in[12];
  const float* Chw  = (const float*)d_in[13];
  const float* Chb  = (const float*)d_in[14];
  const float* tWr  = (const float*)d_in[15];
  const float* tgr  = (const float*)d_in[16];
  const float* tbr  = (const float*)d_in[17];
  const float* tWz  = (const float*)d_in[18];
  const float* tgz  = (const float*)d_in[19];
  const float* tbz  = (const float*)d_in[20];
  const float* tWc  = (const float*)d_in[21];
  const float* tbc  = (const float*)d_in[22];

  short*    wt    = (short*)d_ws;
  float*    pre   = (float*)((char*)d_ws + PRE_OFFB);
  unsigned* flags = (unsigned*)((char*)d_ws + FLAG_OFFB);

  hipMemsetAsync(flags, 0, NFLAGS * sizeof(unsigned), stream);
  hipLaunchKernelGGL(prep_weights, dim3((WT_TOTAL + 255) / 256), dim3(256), 0, stream,
                     Wr, Wz, Wl, Wlt, Cx, Chw, tWr, tWz, tWc, wt);
  hipLaunchKernelGGL(rnn_cluster, dim3(128), dim3(256), 0, stream,
                     x, lengths, gr, br, gz, bz, gl, bl, Chb,
                     tgr, tbr, tgz, tbz, tbc, wt, pre, flags, (float*)d_out);
}

// Round 3
// 19706.367 us; speedup vs baseline: 2.2648x; 1.9522x over previous
//
#include <hip/hip_runtime.h>
#include <hip/hip_bf16.h>

#define T_ 512
#define B_ 128
#define D_ 256
#define H_ 256
#define EPS 1e-5f

typedef __attribute__((ext_vector_type(8))) short short8;
typedef __attribute__((ext_vector_type(4))) short short4v;
typedef __attribute__((ext_vector_type(4))) float f32x4;

// bf16 weight arena layout in d_ws (element offsets, bf16/short):
#define WT1A_OFF 0         // [768][512]  n: 0-255 Wr, 256-511 Wz, 512-767 Wl ; k: 0-255 x, 256-511 h
#define WT1B_OFF 393216    // [512][256]  n: 0-255 Cx, 256-511 Wlt            ; A = x
#define WT1C_OFF 524288    // [256][256]  Ch_w                                 ; A = h
#define WTT_OFF  589824    // [4][768][256] per layer: n 0-255 tWr, 256-511 tWz, 512-767 tWc
#define WTT_PER  196608
#define WT_TOTAL 1376256

// ws byte offsets past the weight arena
#define PRE_OFFB  2752512UL   // f32 [2 parity][8 cl][6 arr][16][256]  (1.57 MB)
#define SLOT_OFFB 4325376UL   // u32 [8 cl][2 parity][16 slots]        (1 KB)
#define NSLOTS    256

__device__ __forceinline__ short f2bf(float f) {
  unsigned u = __builtin_bit_cast(unsigned, f);
  u = (u + 0x7FFFu + ((u >> 16) & 1u)) >> 16;   // RNE
  return (short)u;
}

__device__ __forceinline__ f32x4 zero4() { f32x4 z = {0.f, 0.f, 0.f, 0.f}; return z; }

__device__ __forceinline__ f32x4 mfma16(short8 a, short8 b, f32x4 c) {
  return __builtin_amdgcn_mfma_f32_16x16x32_bf16(a, b, c, 0, 0, 0);
}

__device__ __forceinline__ void red2(float& a, float& b) {
  #pragma unroll
  for (int off = 32; off; off >>= 1) {
    a += __shfl_xor(a, off);
    b += __shfl_xor(b, off);
  }
}

// LayerNorm over 256 values spread across the wave (4/lane) -> sigmoid
__device__ __forceinline__ f32x4 ln_sig(f32x4 v, f32x4 g, f32x4 bb) {
  float s1 = v[0] + v[1] + v[2] + v[3];
  float s2 = v[0]*v[0] + v[1]*v[1] + v[2]*v[2] + v[3]*v[3];
  red2(s1, s2);
  float m = s1 * (1.f / 256.f);
  float var = s2 * (1.f / 256.f) - m * m;
  float rs = rsqrtf((var > 0.f ? var : 0.f) + EPS);
  f32x4 o;
  #pragma unroll
  for (int i = 0; i < 4; ++i) {
    float t = (v[i] - m) * rs * g[i] + bb[i];
    o[i] = 1.f / (1.f + __expf(-t));
  }
  return o;
}

// device-coherent (AGENT scope, sc1 path) 16B load / 4B store into shared preact buffer
__device__ __forceinline__ f32x4 ald4(float* p) {
  unsigned long long* q = (unsigned long long*)p;
  unsigned long long a = __hip_atomic_load(q,     __ATOMIC_RELAXED, __HIP_MEMORY_SCOPE_AGENT);
  unsigned long long b = __hip_atomic_load(q + 1, __ATOMIC_RELAXED, __HIP_MEMORY_SCOPE_AGENT);
  f32x4 v;
  v[0] = __builtin_bit_cast(float, (unsigned)(a & 0xffffffffu));
  v[1] = __builtin_bit_cast(float, (unsigned)(a >> 32));
  v[2] = __builtin_bit_cast(float, (unsigned)(b & 0xffffffffu));
  v[3] = __builtin_bit_cast(float, (unsigned)(b >> 32));
  return v;
}
__device__ __forceinline__ void ast1(float* p, float v) {
  __hip_atomic_store((unsigned*)p, __builtin_bit_cast(unsigned, v),
                     __ATOMIC_RELAXED, __HIP_MEMORY_SCOPE_AGENT);
}

// ---------------- weight prep: f32 -> bf16, transposed to [n][k] ----------------
__global__ void prep_weights(const float* __restrict__ Wr, const float* __restrict__ Wz,
                             const float* __restrict__ Wl, const float* __restrict__ Wlt,
                             const float* __restrict__ Cx, const float* __restrict__ Chw,
                             const float* __restrict__ tWr, const float* __restrict__ tWz,
                             const float* __restrict__ tWc, short* __restrict__ wt) {
  int idx = blockIdx.x * 256 + threadIdx.x;
  if (idx >= WT_TOTAL) return;
  float v;
  if (idx < WT1B_OFF) {                       // WT1a [768][512]
    int n = idx >> 9, k = idx & 511;
    const float* W = (n < 256) ? Wr : (n < 512 ? Wz : Wl);
    v = W[k * 256 + (n & 255)];
  } else if (idx < WT1C_OFF) {                // WT1b [512][256]
    int r = idx - WT1B_OFF;
    int n = r >> 8, k = r & 255;
    v = (n < 256) ? Cx[k * 256 + n] : Wlt[k * 256 + (n - 256)];
  } else if (idx < WTT_OFF) {                 // WT1c [256][256]
    int r = idx - WT1C_OFF;
    int n = r >> 8, k = r & 255;
    v = Chw[k * 256 + n];
  } else {                                    // WTt [4][768][256]
    int r = idx - WTT_OFF;
    int i = r / WTT_PER;
    int rr = r - i * WTT_PER;
    int n = rr >> 8, k = rr & 255;
    const float* W = (n < 256) ? tWr : (n < 512 ? tWz : tWc);
    v = W[(i * 256 + k) * 256 + (n & 255)];
  }
  wt[idx] = f2bf(v);
}

// ------- cluster kernel: 8 clusters (16 rows) x 16 col-slice WGs, 256 thr -------
__global__ __launch_bounds__(256)
void rnn_cluster(const float* __restrict__ x, const int* __restrict__ lengths,
                 const float* __restrict__ gr, const float* __restrict__ br,
                 const float* __restrict__ gz, const float* __restrict__ bz,
                 const float* __restrict__ gl, const float* __restrict__ bl,
                 const float* __restrict__ Chb,
                 const float* __restrict__ tgr, const float* __restrict__ tbr,
                 const float* __restrict__ tgz, const float* __restrict__ tbz,
                 const float* __restrict__ tbc,
                 const short* __restrict__ W, float* __restrict__ pre,
                 unsigned* __restrict__ slots, float* __restrict__ out) {

  __shared__ __align__(16) char smem[32768];
  char*  HBF = smem;                       // [16][256] bf16, XOR-swizzled (8 KB)
  char*  XBF = smem + 8192;                // [16][256] bf16, XOR-swizzled (8 KB)
  float* HF  = (float*)(smem + 16384);     // [16][256] f32 h master       (16 KB)
  __shared__ int wg_dead;

  const int tid = threadIdx.x;
  const int w   = tid >> 6, l = tid & 63;
  const int la  = l & 15, lh = l >> 4;
  const int amask = (la & 7) << 4;
  const int bid = blockIdx.x;
  const int cl  = bid & 7;                 // cluster
  const int sl  = bid >> 3;                // column slice 0..15
  const int rb0 = cl * 16;                 // batch rows
  const int c0  = sl * 16;                 // output columns [c0, c0+16)
  const int c0e = 4 * l;                   // elementwise columns 4l..4l+3

  for (int i = tid; i < 1024; i += 256) ((short4v*)HBF)[i] = (short4v){0, 0, 0, 0};
  for (int i = tid; i < 1024; i += 256) ((f32x4*)HF)[i] = zero4();
  if (tid == 0) wg_dead = 0;

  int maxlen = 0;
  for (int i = 0; i < 16; ++i) {
    int v = lengths[rb0 + i];
    maxlen = maxlen > v ? maxlen : v;
  }
  int lenr[4];
  #pragma unroll
  for (int i = 0; i < 4; ++i) lenr[i] = lengths[rb0 + 4 * w + i];

  unsigned* slotb = slots + cl * 32;       // [2 parity][16]

  // post tag R+1 to my slot (after vmcnt-drain + barrier), wait for all 16.
  // No wbl2/inv needed: all exchanged data moves via agent-scope (sc1) ops.
  auto csync = [&](int R) {
    asm volatile("s_waitcnt vmcnt(0)" ::: "memory");   // my wave's sc1 stores visible
    __syncthreads();                                    // => ALL waves' stores visible
    if (tid == 0)
      __hip_atomic_store(slotb + (R & 1) * 16 + sl, (unsigned)(R + 1),
                         __ATOMIC_RELAXED, __HIP_MEMORY_SCOPE_AGENT);
    if (!wg_dead) {
      unsigned tag = (unsigned)(R + 1);
      unsigned* sp = slotb + (R & 1) * 16 + (l & 15);   // lane l waits on WG l&15
      int it = 0;
      while (__hip_atomic_load(sp, __ATOMIC_RELAXED, __HIP_MEMORY_SCOPE_AGENT) < tag) {
        if (++it > 200000) { wg_dead = 1; break; }
        __builtin_amdgcn_s_sleep(2);
      }
    }
    asm volatile("" ::: "memory");
  };

  __syncthreads();

  for (int t = 0; t < maxlen; ++t) {
    // ---- stage x_t -> XBF (bf16, swizzled) ----
    {
      const float* xt = x + ((size_t)t * B_ + rb0) * D_;
      for (int c = tid; c < 1024; c += 256) {
        int row = c >> 6, j = c & 63;
        f32x4 v = *(const f32x4*)(xt + row * D_ + 4 * j);
        short4v s = { f2bf(v[0]), f2bf(v[1]), f2bf(v[2]), f2bf(v[3]) };
        *(short4v*)(XBF + row * 512 + ((8 * j) ^ ((row & 7) << 4))) = s;
      }
    }
    __syncthreads();

    // ================= round G =================
    int R = t * 5;
    {
      float* P = pre + (size_t)(((R & 1) * 8 + cl) * 6) * 4096;
      if (w < 3) {                         // waves 0..2: gate w slice, K=512
        f32x4 acc = zero4();
        const short* bp = W + WT1A_OFF + (size_t)(w * 256 + c0 + la) * 512 + lh * 8;
        #pragma unroll
        for (int kf = 0; kf < 16; ++kf) {
          int aoff = la * 512 + ((((kf & 7) * 64) + lh * 16) ^ amask);
          short8 a = (kf < 8) ? *(const short8*)(XBF + aoff) : *(const short8*)(HBF + aoff);
          acc = mfma16(a, *(const short8*)(bp + kf * 32), acc);
        }
        #pragma unroll
        for (int i = 0; i < 4; ++i) ast1(P + w * 4096 + (lh * 4 + i) * 256 + c0 + la, acc[i]);
      } else {                             // wave 3: xcx, xwl, hch (K=256)
        f32x4 a0 = zero4(), a1 = zero4(), a2 = zero4();
        const short* b0 = W + WT1B_OFF + (size_t)(c0 + la) * 256 + lh * 8;
        const short* b1 = W + WT1B_OFF + (size_t)(256 + c0 + la) * 256 + lh * 8;
        const short* b2 = W + WT1C_OFF + (size_t)(c0 + la) * 256 + lh * 8;
        #pragma unroll
        for (int kf = 0; kf < 8; ++kf) {
          int aoff = la * 512 + (((kf * 64) + lh * 16) ^ amask);
          short8 ax = *(const short8*)(XBF + aoff);
          short8 ah = *(const short8*)(HBF + aoff);
          a0 = mfma16(ax, *(const short8*)(b0 + kf * 32), a0);
          a1 = mfma16(ax, *(const short8*)(b1 + kf * 32), a1);
          a2 = mfma16(ah, *(const short8*)(b2 + kf * 32), a2);
        }
        #pragma unroll
        for (int i = 0; i < 4; ++i) {
          ast1(P + 3 * 4096 + (lh * 4 + i) * 256 + c0 + la, a0[i]);
          ast1(P + 4 * 4096 + (lh * 4 + i) * 256 + c0 + la, a1[i]);
          ast1(P + 5 * 4096 + (lh * 4 + i) * 256 + c0 + la, a2[i]);
        }
      }
      csync(R);

      // ---- redundant GRU-cell elementwise: wave w -> rows 4w..4w+3 ----
      f32x4 g4r = *(const f32x4*)(gr + c0e), b4r = *(const f32x4*)(br + c0e);
      f32x4 g4z = *(const f32x4*)(gz + c0e), b4z = *(const f32x4*)(bz + c0e);
      f32x4 g4l = *(const f32x4*)(gl + c0e), b4l = *(const f32x4*)(bl + c0e);
      f32x4 cb4 = *(const f32x4*)(Chb + c0e);
      #pragma unroll
      for (int i = 0; i < 4; ++i) {
        int row = 4 * w + i;
        float* Pr = P + row * 256 + c0e;
        f32x4 pr  = ald4(Pr);
        f32x4 pz  = ald4(Pr + 4096);
        f32x4 pl  = ald4(Pr + 2 * 4096);
        f32x4 xcx = ald4(Pr + 3 * 4096);
        f32x4 xwl = ald4(Pr + 4 * 4096);
        f32x4 hch = ald4(Pr + 5 * 4096);
        f32x4 r4 = ln_sig(pr, g4r, b4r);
        f32x4 z4 = ln_sig(pz, g4z, b4z);
        f32x4 l4 = ln_sig(pl, g4l, b4l);
        f32x4 h = *(const f32x4*)&HF[row * 256 + c0e];
        f32x4 hn;
        #pragma unroll
        for (int q = 0; q < 4; ++q) {
          float n = tanhf(xcx[q] + r4[q] * (hch[q] + cb4[q])) + l4[q] * xwl[q];
          hn[q] = (1.f - z4[q]) * h[q] + z4[q] * n;
        }
        if (t < lenr[i]) {
          *(f32x4*)&HF[row * 256 + c0e] = hn;
          short4v sv = { f2bf(hn[0]), f2bf(hn[1]), f2bf(hn[2]), f2bf(hn[3]) };
          *(short4v*)(HBF + row * 512 + ((8 * l) ^ ((row & 7) << 4))) = sv;
        }
      }
    }
    __syncthreads();

    // ================= transition layers =================
    #pragma unroll 1
    for (int li = 0; li < 4; ++li) {
      R = t * 5 + 1 + li;
      float* P = pre + (size_t)(((R & 1) * 8 + cl) * 6) * 4096;
      if (w < 3) {                         // waves 0..2: tr/tz/tc slice, K=256
        f32x4 acc = zero4();
        const short* bp = W + WTT_OFF + li * WTT_PER + (size_t)(w * 256 + c0 + la) * 256 + lh * 8;
        #pragma unroll
        for (int kf = 0; kf < 8; ++kf) {
          int aoff = la * 512 + (((kf * 64) + lh * 16) ^ amask);
          short8 a = *(const short8*)(HBF + aoff);
          acc = mfma16(a, *(const short8*)(bp + kf * 32), acc);
        }
        #pragma unroll
        for (int i = 0; i < 4; ++i) ast1(P + w * 4096 + (lh * 4 + i) * 256 + c0 + la, acc[i]);
      }
      csync(R);

      // ---- redundant transition elementwise ----
      f32x4 g4r = *(const f32x4*)(tgr + li * 256 + c0e), b4r = *(const f32x4*)(tbr + li * 256 + c0e);
      f32x4 g4z = *(const f32x4*)(tgz + li * 256 + c0e), b4z = *(const f32x4*)(tbz + li * 256 + c0e);
      f32x4 cb4 = *(const f32x4*)(tbc + li * 256 + c0e);
      #pragma unroll
      for (int i = 0; i < 4; ++i) {
        int row = 4 * w + i;
        float* Pr = P + row * 256 + c0e;
        f32x4 pr = ald4(Pr);
        f32x4 pz = ald4(Pr + 4096);
        f32x4 pc = ald4(Pr + 2 * 4096);
        f32x4 ri = ln_sig(pr, g4r, b4r);
        f32x4 zi = ln_sig(pz, g4z, b4z);
        f32x4 h = *(const f32x4*)&HF[row * 256 + c0e];
        f32x4 hn;
        #pragma unroll
        for (int q = 0; q < 4; ++q) {
          float n = tanhf(ri[q] * (pc[q] + cb4[q]));
          hn[q] = (1.f - zi[q]) * n + zi[q] * h[q];
        }
        bool act = t < lenr[i];
        if (act) {
          *(f32x4*)&HF[row * 256 + c0e] = hn;
          short4v sv = { f2bf(hn[0]), f2bf(hn[1]), f2bf(hn[2]), f2bf(hn[3]) };
          *(short4v*)(HBF + row * 512 + ((8 * l) ^ ((row & 7) << 4))) = sv;
        }
        if (li == 3 && (l >> 2) == sl) {   // this WG owns cols [c0,c0+16)
          f32x4 o = act ? hn : zero4();
          *(f32x4*)(out + ((size_t)t * B_ + rb0 + row) * H_ + c0e) = o;
        }
      }
      __syncthreads();
    }
  }

  // tail: zero this WG's column slice past the cluster's longest sequence
  for (int t = maxlen; t < T_; ++t) {
    if (tid < 64) {
      int row = tid >> 2, cc = (tid & 3) * 4;
      *(f32x4*)(out + ((size_t)t * B_ + rb0 + row) * H_ + c0 + cc) = zero4();
    }
  }
}

extern "C" void kernel_launch(void* const* d_in, const int* in_sizes, int n_in,
                              void* d_out, int out_size, void* d_ws, size_t ws_size,
                              hipStream_t stream) {
  const float* x    = (const float*)d_in[0];
  const int* lengths = (const int*)d_in[1];
  const float* Wr   = (const float*)d_in[2];
  const float* gr   = (const float*)d_in[3];
  const float* br   = (const float*)d_in[4];
  const float* Wz   = (const float*)d_in[5];
  const float* gz   = (const float*)d_in[6];
  const float* bz   = (const float*)d_in[7];
  const float* Wl   = (const float*)d_in[8];
  const float* gl   = (const float*)d_in[9];
  const float* bl   = (const float*)d_in[10];
  const float* Wlt  = (const float*)d_in[11];
  const float* Cx   = (const float*)d_in[12];
  const float* Chw  = (const float*)d_in[13];
  const float* Chb  = (const float*)d_in[14];
  const float* tWr  = (const float*)d_in[15];
  const float* tgr  = (const float*)d_in[16];
  const float* tbr  = (const float*)d_in[17];
  const float* tWz  = (const float*)d_in[18];
  const float* tgz  = (const float*)d_in[19];
  const float* tbz  = (const float*)d_in[20];
  const float* tWc  = (const float*)d_in[21];
  const float* tbc  = (const float*)d_in[22];

  short*    wt    = (short*)d_ws;
  float*    pre   = (float*)((char*)d_ws + PRE_OFFB);
  unsigned* slots = (unsigned*)((char*)d_ws + SLOT_OFFB);

  hipMemsetAsync(slots, 0, NSLOTS * sizeof(unsigned), stream);
  hipLaunchKernelGGL(prep_weights, dim3((WT_TOTAL + 255) / 256), dim3(256), 0, stream,
                     Wr, Wz, Wl, Wlt, Cx, Chw, tWr, tWz, tWc, wt);
  hipLaunchKernelGGL(rnn_cluster, dim3(128), dim3(256), 0, stream,
                     x, lengths, gr, br, gz, bz, gl, bl, Chb,
                     tgr, tbr, tgz, tbz, tbc, wt, pre, slots, (float*)d_out);
}